// Round 5
// baseline (98.923 us; speedup 1.0000x reference)
//
#include <hip/hip_runtime.h>

// ---- types ----------------------------------------------------------------
typedef __attribute__((ext_vector_type(8))) short bf16x8;     // 8 bf16 (4 VGPR)
typedef __attribute__((ext_vector_type(4))) float f32x4;
typedef __attribute__((ext_vector_type(4))) unsigned short us4;
typedef __attribute__((ext_vector_type(8))) unsigned short us8;

#define MFMA(a, b, c) __builtin_amdgcn_mfma_f32_16x16x32_bf16((a), (b), (c), 0, 0, 0)

__device__ __forceinline__ unsigned short f2bf(float f) {
  unsigned u = __builtin_bit_cast(unsigned, f);
  u = (u + 0x7fffu + ((u >> 16) & 1u)) >> 16;  // RNE
  return (unsigned short)u;
}

__device__ __forceinline__ void gload16(const void* g, void* l) {
  __builtin_amdgcn_global_load_lds((const __attribute__((address_space(1))) void*)g,
                                   (__attribute__((address_space(3))) void*)l,
                                   16, 0, 0);
}

// 128B-row swizzled fragment read: phys = byte ^ ((row&7)<<4).
// 16 lanes reading rows base..base+15 at the same 16B col land on
// chunk-slot lg^(row&7): all 8 slots twice -> conflict-free.
__device__ __forceinline__ bf16x8 readfrag(const unsigned short* buf, int row, int kbyte) {
  int byte = row * 128 + kbyte;
  byte ^= (row & 7) << 4;
  return *(const bf16x8*)((const char*)buf + byte);
}

// ---- kernel 1: cast x -> bf16 (float4 vectorized) --------------------------
__global__ void cast_x_kernel(const float* __restrict__ x,
                              unsigned short* __restrict__ xb, int n4) {
  int id = blockIdx.x * blockDim.x + threadIdx.x;
  if (id >= n4) return;
  float4 v = ((const float4*)x)[id];
  us4 o = { f2bf(v.x), f2bf(v.y), f2bf(v.z), f2bf(v.w) };
  ((us4*)xb)[id] = o;
}

// ---- kernel 2: W [768][2304] -> Wt [2304][768] bf16 (tiled transpose) ------
__global__ void castw_kernel(const float* __restrict__ W,
                             unsigned short* __restrict__ Wt) {
  __shared__ unsigned short tile[32][33];
  int bn = blockIdx.x * 32;
  int bk = blockIdx.y * 32;
  int lx = threadIdx.x & 31, ly = threadIdx.x >> 5;  // 32 x 8
#pragma unroll
  for (int i = 0; i < 32; i += 8)
    tile[ly + i][lx] = f2bf(W[(bk + ly + i) * 2304 + bn + lx]);
  __syncthreads();
#pragma unroll
  for (int i = 0; i < 32; i += 8)
    Wt[(bn + ly + i) * 768 + bk + lx] = tile[lx][ly + i];
}

// ---- kernel 3: QKV GEMM ----------------------------------------------------
// BM=256 BN=128 BK=64, 8 waves (4Mx2N), wave-tile 64x64.
// A/B triple-buffered (144KB LDS), 2-ahead prefetch, counted vmcnt(6).
// 2 phases x 16 MFMA per K-tile; conflict-free (row&7)<<4 LDS swizzle.
__global__ __launch_bounds__(512, 2) void qkv_gemm_kernel(
    const unsigned short* __restrict__ xb, const unsigned short* __restrict__ wt,
    const float* __restrict__ bias,
    unsigned short* __restrict__ qb, unsigned short* __restrict__ kb,
    unsigned short* __restrict__ vb) {
  __shared__ unsigned short lds[73728];  // A 3x16384 elems @0, B 3x8192 @49152
  const int tid = threadIdx.x;
  const int lane = tid & 63, wid = tid >> 6;
  const int wm = wid >> 1, wn = wid & 1;   // wave-tile 64x64
  const int l15 = lane & 15, lg = lane >> 4;

  int bid = blockIdx.x;
  int xcd = bid & 7, c = bid >> 3;
  int mb = (xcd & 3) * 8 + (c & 7);
  int nb = (xcd >> 2) * 9 + (c >> 3);
  const int m0 = mb * 256, n0 = nb * 128;

  const unsigned short* Ab_g = xb + (size_t)m0 * 768;
  const unsigned short* Bb_g = wt + (size_t)n0 * 768;

  // staging: linear LDS dest, inverse-swizzled global source (64-elem rows)
  int eA[4], sA[4], eB[2], sB[2];
#pragma unroll
  for (int i = 0; i < 4; ++i) {
    int e = (i * 512 + tid) * 8, row = e >> 6;
    eA[i] = e;
    sA[i] = row * 768 + ((e ^ ((row & 7) << 3)) & 63);
  }
#pragma unroll
  for (int i = 0; i < 2; ++i) {
    int e = (i * 512 + tid) * 8, row = e >> 6;
    eB[i] = e;
    sB[i] = row * 768 + ((e ^ ((row & 7) << 3)) & 63);
  }

#define SA(buf, k0, i) gload16(Ab_g + sA[i] + (k0), &lds[(buf) * 16384 + eA[i]])
#define SB(buf, k0, i) gload16(Bb_g + sB[i] + (k0), &lds[49152 + (buf) * 8192 + eB[i]])

  f32x4 acc[4][4] = {};
  bf16x8 bfr[4][2];

  // prologue: stage t0 (6) + t1 (6); wait t0 complete (allow newest 6)
  SA(0, 0, 0); SA(0, 0, 1); SA(0, 0, 2); SA(0, 0, 3);
  SB(0, 0, 0); SB(0, 0, 1);
  SA(1, 64, 0); SA(1, 64, 1); SA(1, 64, 2); SA(1, 64, 3);
  SB(1, 64, 0); SB(1, 64, 1);
  asm volatile("s_waitcnt vmcnt(6)" ::: "memory");
  __builtin_amdgcn_s_barrier();

// phase: ds_read -> issue stage -> barrier -> lgkmcnt(0) -> 16 MFMA -> [wait] -> barrier
#define GPHASE(cc_, P, STG, EW)                                                   \
  {                                                                               \
    const unsigned short* Abuf = &lds[(cc_) * 16384];                             \
    const unsigned short* Bbuf = &lds[49152 + (cc_) * 8192];                      \
    bf16x8 afr[2][2];                                                             \
    _Pragma("unroll") for (int m2 = 0; m2 < 2; ++m2)                              \
        _Pragma("unroll") for (int kk = 0; kk < 2; ++kk)                          \
            afr[m2][kk] =                                                         \
        readfrag(Abuf, wm * 64 + ((P) * 2 + m2) * 16 + l15, kk * 64 + lg * 16);   \
    if ((P) == 0) {                                                               \
      _Pragma("unroll") for (int nf = 0; nf < 4; ++nf)                            \
          _Pragma("unroll") for (int kk = 0; kk < 2; ++kk)                        \
              bfr[nf][kk] =                                                       \
          readfrag(Bbuf, wn * 64 + nf * 16 + l15, kk * 64 + lg * 16);             \
    }                                                                             \
    STG;                                                                          \
    __builtin_amdgcn_sched_barrier(0);                                            \
    __builtin_amdgcn_s_barrier();                                                 \
    asm volatile("s_waitcnt lgkmcnt(0)" ::: "memory");                            \
    __builtin_amdgcn_sched_barrier(0);                                            \
    __builtin_amdgcn_s_setprio(1);                                                \
    _Pragma("unroll") for (int m2 = 0; m2 < 2; ++m2)                              \
        _Pragma("unroll") for (int nf = 0; nf < 4; ++nf)                          \
            _Pragma("unroll") for (int kk = 0; kk < 2; ++kk)                      \
                acc[(P) * 2 + m2][nf] =                                           \
        MFMA(afr[m2][kk], bfr[nf][kk], acc[(P) * 2 + m2][nf]);                    \
    __builtin_amdgcn_s_setprio(0);                                                \
    EW;                                                                           \
    __builtin_amdgcn_sched_barrier(0);                                            \
    __builtin_amdgcn_s_barrier();                                                 \
  }

  // main loop: tile t consumes buf t%3, stages t+2 into (t+2)%3.
  // end-of-tile vmcnt(6): newest 6 = t+2's; guarantees t+1 landed.
  int cc = 0;
  for (int t = 0; t < 10; ++t) {
    int c2 = cc + 2; if (c2 >= 3) c2 -= 3;
    int k2 = (t + 2) * 64;
    GPHASE(cc, 0, { SA(c2, k2, 0); SA(c2, k2, 1); SB(c2, k2, 0); }, );
    GPHASE(cc, 1, { SA(c2, k2, 2); SA(c2, k2, 3); SB(c2, k2, 1); },
           asm volatile("s_waitcnt vmcnt(6)" ::: "memory"));
    cc = (cc == 2) ? 0 : cc + 1;
  }
  // t=10: nothing to stage; drain tile 11's loads at end
  GPHASE(cc, 0, , );
  GPHASE(cc, 1, , asm volatile("s_waitcnt vmcnt(0)" ::: "memory"));
  cc = (cc == 2) ? 0 : cc + 1;
  // t=11
  GPHASE(cc, 0, , );
  GPHASE(cc, 1, , );

  __syncthreads();  // reuse LDS for epilogue

  const int sec = n0 / 768;  // 0=q,1=k,2=v (block-uniform)
  float bcol[4];
#pragma unroll
  for (int nf = 0; nf < 4; ++nf) bcol[nf] = bias[n0 + wn * 64 + nf * 16 + l15];

  if (sec < 2) {
    unsigned short* ct = lds;  // [256][128] = 32768 elems (fits 73728)
#pragma unroll
    for (int mf = 0; mf < 4; ++mf)
#pragma unroll
      for (int nf = 0; nf < 4; ++nf)
#pragma unroll
        for (int r = 0; r < 4; ++r)
          ct[(wm * 64 + mf * 16 + lg * 4 + r) * 128 + wn * 64 + nf * 16 + l15] =
              f2bf(acc[mf][nf][r] + bcol[nf]);
    __syncthreads();
    unsigned short* dstbase = (sec == 0) ? qb : kb;
    const int hbase = (n0 - sec * 768) >> 6;
    const int g8 = tid >> 3, l8 = tid & 7;
#pragma unroll
    for (int j = 0; j < 8; ++j) {
      int chunk = j * 64 + g8;  // 0..511 = row*2 + hh
      int row = chunk >> 1, hh = chunk & 1;
      us8 v = *(const us8*)&ct[row * 128 + hh * 64 + l8 * 8];
      int t = m0 + row, bb = t >> 10, tt = t & 1023;
      *(us8*)(dstbase + ((size_t)((bb * 12 + hbase + hh) * 1024 + tt)) * 64 + l8 * 8) = v;
    }
  } else {
    // v transposed [B,H,64,T]: us4 stores along t
#pragma unroll
    for (int nf = 0; nf < 4; ++nf) {
      int cc2 = (n0 - 1536) + wn * 64 + nf * 16 + l15;
      int h = cc2 >> 6, d = cc2 & 63;
#pragma unroll
      for (int mf = 0; mf < 4; ++mf) {
        int row0 = m0 + wm * 64 + mf * 16 + lg * 4;
        int bb = row0 >> 10, t0 = row0 & 1023;
        us4 o;
#pragma unroll
        for (int r = 0; r < 4; ++r) o[r] = f2bf(acc[mf][nf][r] + bcol[nf]);
        *(us4*)(vb + ((size_t)((bb * 12 + h) * 64 + d)) * 1024 + t0) = o;
      }
    }
  }
#undef SA
#undef SB
#undef GPHASE
}

// ---- kernel 4: causal ReLU attention (unchanged from R4) -------------------
__global__ __launch_bounds__(512, 2) void attn_kernel(
    const unsigned short* __restrict__ qb, const unsigned short* __restrict__ kb,
    const unsigned short* __restrict__ vb, float* __restrict__ out) {
  __shared__ unsigned short lds[65536];
  const int tid = threadIdx.x;
  const int lane = tid & 63, wid = tid >> 6;
  const int qs = wid >> 1, ks = wid & 1;
  const int l15 = lane & 15, lg = lane >> 4;

  int bid = blockIdx.x;
  int xcd = bid & 7, c = bid >> 3;       // c 0..47
  int bh = xcd * 12 + (c % 12);
  int byq = 3 - (c / 12);                // heavy q-blocks first
  const int b = bh / 12, h = bh % 12;
  const size_t base = (size_t)bh * 65536;
  const int Q = byq * 4 + qs;
  const int qr0 = byq * 256 + qs * 64;

  bf16x8 aq[4][2];
#pragma unroll
  for (int mf = 0; mf < 4; ++mf)
#pragma unroll
    for (int kk = 0; kk < 2; ++kk)
      aq[mf][kk] = *(const bf16x8*)(qb + base + (size_t)(qr0 + mf * 16 + l15) * 64 +
                                    kk * 32 + lg * 8);

  const int e = tid * 8;
  const int row = e >> 6;
  const int esw = e ^ ((row & 7) << 3);

#define ASTAGE(buf, i_)                                                            \
  {                                                                                \
    int kt0 = 2 * (i_);                                                            \
    gload16(kb + base + (size_t)kt0 * 4096 + esw, &lds[(buf) * 8192 + e]);         \
    gload16(kb + base + (size_t)(kt0 + 1) * 4096 + esw,                            \
            &lds[(buf) * 8192 + 4096 + e]);                                        \
    gload16(vb + base + (size_t)row * 1024 + kt0 * 64 + (esw & 63),                \
            &lds[16384 + (buf) * 8192 + e]);                                       \
    gload16(vb + base + (size_t)row * 1024 + (kt0 + 1) * 64 + (esw & 63),          \
            &lds[16384 + (buf) * 8192 + 4096 + e]);                                \
  }

  f32x4 o[4][4] = {};
  unsigned short* Sb = &lds[32768 + wid * 4096];

  const int niter = 2 * byq + 2;
  ASTAGE(0, 0);
  asm volatile("s_waitcnt vmcnt(0)" ::: "memory");
  __builtin_amdgcn_s_barrier();

  for (int i = 0; i < niter; ++i) {
    const int cur = i & 1;
    if (i + 1 < niter) ASTAGE(cur ^ 1, i + 1);
    const int kt = 2 * i + ks;
    if (kt <= Q) {
      const unsigned short* Kb = &lds[cur * 8192 + ks * 4096];
      const unsigned short* Vb = &lds[16384 + cur * 8192 + ks * 4096];
      bf16x8 bk[4][2];
#pragma unroll
      for (int nf = 0; nf < 4; ++nf)
#pragma unroll
        for (int kk = 0; kk < 2; ++kk)
          bk[nf][kk] = readfrag(Kb, nf * 16 + l15, kk * 64 + lg * 16);
      const bool diag = (kt == Q);
      __builtin_amdgcn_s_setprio(1);
#pragma unroll
      for (int mf = 0; mf < 4; ++mf)
#pragma unroll
        for (int nf = 0; nf < 4; ++nf) {
          f32x4 s = {};
          s = MFMA(aq[mf][0], bk[nf][0], s);
          s = MFMA(aq[mf][1], bk[nf][1], s);
          int colk = nf * 16 + l15;
#pragma unroll
          for (int r = 0; r < 4; ++r) {
            int rowq = mf * 16 + lg * 4 + r;
            float v = fmaxf(s[r] * 0.125f, 0.0f);
            if (diag && colk > rowq) v = 0.0f;
            int byte = (rowq * 128 + colk * 2) ^ ((rowq & 7) << 4);
            *(unsigned short*)((char*)Sb + byte) = f2bf(v);
          }
        }
      __builtin_amdgcn_s_setprio(0);
      bf16x8 pa[4][2];
#pragma unroll
      for (int mf = 0; mf < 4; ++mf)
#pragma unroll
        for (int kk = 0; kk < 2; ++kk)
          pa[mf][kk] = readfrag(Sb, mf * 16 + l15, kk * 64 + lg * 16);
      __builtin_amdgcn_s_setprio(1);
#pragma unroll
      for (int mf = 0; mf < 4; ++mf)
#pragma unroll
        for (int df = 0; df < 4; ++df)
#pragma unroll
          for (int kk = 0; kk < 2; ++kk)
            o[mf][df] = MFMA(pa[mf][kk], readfrag(Vb, df * 16 + l15, kk * 64 + lg * 16),
                             o[mf][df]);
      __builtin_amdgcn_s_setprio(0);
    }
    asm volatile("s_waitcnt vmcnt(0)" ::: "memory");
    __builtin_amdgcn_sched_barrier(0);
    __builtin_amdgcn_s_barrier();
  }
#undef ASTAGE

  float* fr = (float*)lds;
  if (ks == 1) {
#pragma unroll
    for (int mf = 0; mf < 4; ++mf)
#pragma unroll
      for (int df = 0; df < 4; ++df)
#pragma unroll
        for (int r = 0; r < 4; ++r) {
          int rowq = mf * 16 + lg * 4 + r, col = df * 16 + l15;
          int idx = (qs * 4096 + rowq * 64 + col) ^ ((rowq & 4) << 2);
          fr[idx] = o[mf][df][r];
        }
  }
  __syncthreads();
  if (ks == 0) {
#pragma unroll
    for (int mf = 0; mf < 4; ++mf)
#pragma unroll
      for (int df = 0; df < 4; ++df)
#pragma unroll
        for (int r = 0; r < 4; ++r) {
          int rowq = mf * 16 + lg * 4 + r, col = df * 16 + l15;
          int idx = (qs * 4096 + rowq * 64 + col) ^ ((rowq & 4) << 2);
          float v = o[mf][df][r] + fr[idx];
          out[(size_t)(b * 1024 + qr0 + rowq) * 768 + h * 64 + col] = v;
        }
  }
}

// ---- launch ----------------------------------------------------------------
extern "C" void kernel_launch(void* const* d_in, const int* in_sizes, int n_in,
                              void* d_out, int out_size, void* d_ws, size_t ws_size,
                              hipStream_t stream) {
  const float* x = (const float*)d_in[0];
  const float* W = (const float*)d_in[1];
  const float* bias = (const float*)d_in[2];
  float* out = (float*)d_out;

  unsigned short* xb = (unsigned short*)d_ws;  // 6291456 elems
  unsigned short* wt = xb + 6291456;           // 1769472 (Wt [2304][768])
  unsigned short* qb = wt + 1769472;           // [B,H,T,64]
  unsigned short* kb = qb + 6291456;
  unsigned short* vb = kb + 6291456;           // [B,H,64,T]

  cast_x_kernel<<<6144, 256, 0, stream>>>(x, xb, 1572864);
  castw_kernel<<<dim3(72, 24), 256, 0, stream>>>(W, wt);
  qkv_gemm_kernel<<<576, 512, 0, stream>>>(xb, wt, bias, qb, kb, vb);
  attn_kernel<<<384, 512, 0, stream>>>(qb, kb, vb, out);
}

// Round 6
// 86.997 us; speedup vs baseline: 1.1371x; 1.1371x over previous
//
#include <hip/hip_runtime.h>

// ---- types ----------------------------------------------------------------
typedef __attribute__((ext_vector_type(8))) short bf16x8;     // 8 bf16 (4 VGPR)
typedef __attribute__((ext_vector_type(4))) float f32x4;
typedef __attribute__((ext_vector_type(4))) unsigned short us4;
typedef __attribute__((ext_vector_type(8))) unsigned short us8;

#define MFMA(a, b, c) __builtin_amdgcn_mfma_f32_16x16x32_bf16((a), (b), (c), 0, 0, 0)

__device__ __forceinline__ unsigned short f2bf(float f) {
  unsigned u = __builtin_bit_cast(unsigned, f);
  u = (u + 0x7fffu + ((u >> 16) & 1u)) >> 16;  // RNE
  return (unsigned short)u;
}

__device__ __forceinline__ void gload16(const void* g, void* l) {
  __builtin_amdgcn_global_load_lds((const __attribute__((address_space(1))) void*)g,
                                   (__attribute__((address_space(3))) void*)l,
                                   16, 0, 0);
}

// 128B-row swizzled fragment read: phys = byte ^ ((row&7)<<4).
// 16 lanes reading 16 consecutive rows at one 16B col hit all 8 chunk-slots
// twice -> conflict-free (2-way aliasing is free).
__device__ __forceinline__ bf16x8 readfrag(const unsigned short* buf, int row, int kbyte) {
  int byte = row * 128 + kbyte;
  byte ^= (row & 7) << 4;
  return *(const bf16x8*)((const char*)buf + byte);
}

// ---- kernel 1: cast x -> bf16 (float4 vectorized) --------------------------
__global__ void cast_x_kernel(const float* __restrict__ x,
                              unsigned short* __restrict__ xb, int n4) {
  int id = blockIdx.x * blockDim.x + threadIdx.x;
  if (id >= n4) return;
  float4 v = ((const float4*)x)[id];
  us4 o = { f2bf(v.x), f2bf(v.y), f2bf(v.z), f2bf(v.w) };
  ((us4*)xb)[id] = o;
}

// ---- kernel 2: W [768][2304] -> Wt [2304][768] bf16 (tiled transpose) ------
__global__ void castw_kernel(const float* __restrict__ W,
                             unsigned short* __restrict__ Wt) {
  __shared__ unsigned short tile[32][33];
  int bn = blockIdx.x * 32;
  int bk = blockIdx.y * 32;
  int lx = threadIdx.x & 31, ly = threadIdx.x >> 5;  // 32 x 8
#pragma unroll
  for (int i = 0; i < 32; i += 8)
    tile[ly + i][lx] = f2bf(W[(bk + ly + i) * 2304 + bn + lx]);
  __syncthreads();
#pragma unroll
  for (int i = 0; i < 32; i += 8)
    Wt[(bn + ly + i) * 768 + bk + lx] = tile[lx][ly + i];
}

// ---- kernel 3: QKV GEMM ----------------------------------------------------
// BM=BN=128, BK=64, 4 waves (2x2), wave-tile 64x64.
// A triple-, B double-buffered: 80KB LDS -> 2 blocks/CU (cross-block overlap:
// independent barrier domains keep the MFMA pipe fed through sync stalls).
// Grid 1152 -> 4.5 rounds over 2 slots (~90% tail vs 75% at 576x1).
__global__ __launch_bounds__(256, 2) void qkv_gemm_kernel(
    const unsigned short* __restrict__ xb, const unsigned short* __restrict__ wt,
    const float* __restrict__ bias,
    unsigned short* __restrict__ qb, unsigned short* __restrict__ kb,
    unsigned short* __restrict__ vb) {
  __shared__ unsigned short lds[40960];  // A 3x8192 elems @0, B 2x8192 @24576 = 80KB
  const int tid = threadIdx.x;
  const int lane = tid & 63, wid = tid >> 6;
  const int wm = wid >> 1, wn = wid & 1;   // wave-tile 64x64
  const int l15 = lane & 15, lg = lane >> 4;

  // XCD swizzle: 1152 = 8 XCDs x 144. Per XCD: 8 m-tiles x 18 n-tiles,
  // m fastest (A panel 1.6MB L2-resident; B panel per n-tile 196KB).
  int bid = blockIdx.x;
  int xcd = bid & 7, c = bid >> 3;       // c 0..143
  int mb = xcd * 8 + (c & 7);            // 0..63
  int nb = c >> 3;                       // 0..17
  const int m0 = mb * 128, n0 = nb * 128;

  const unsigned short* Ab_g = xb + (size_t)m0 * 768;
  const unsigned short* Bb_g = wt + (size_t)n0 * 768;

  // staging: linear LDS dest, inverse-swizzled global source (64-elem rows)
  int eA[4], sA[4];
#pragma unroll
  for (int i = 0; i < 4; ++i) {
    int e = (i * 256 + tid) * 8, row = e >> 6;
    eA[i] = e;
    sA[i] = row * 768 + ((e ^ ((row & 7) << 3)) & 63);
  }

#define SA(buf, k0, i) gload16(Ab_g + sA[i] + (k0), &lds[(buf) * 8192 + eA[i]])
#define SB(buf, k0, i) gload16(Bb_g + sA[i] + (k0), &lds[24576 + (buf) * 8192 + eA[i]])

  f32x4 acc[4][4] = {};
  bf16x8 bfr[4][2];

  // prologue: A0(4), B0(4), A1(4); vmcnt(4) -> A0,B0 landed (A1 may fly)
  SA(0, 0, 0); SA(0, 0, 1); SA(0, 0, 2); SA(0, 0, 3);
  SB(0, 0, 0); SB(0, 0, 1); SB(0, 0, 2); SB(0, 0, 3);
  SA(1, 64, 0); SA(1, 64, 1); SA(1, 64, 2); SA(1, 64, 3);
  asm volatile("s_waitcnt vmcnt(4)" ::: "memory");
  __builtin_amdgcn_s_barrier();

// phase: ds_read -> issue stage -> barrier -> lgkmcnt(0) -> 16 MFMA -> [wait] -> barrier
#define GPHASE(cA_, cB_, P, STG, EW)                                              \
  {                                                                               \
    const unsigned short* Abuf = &lds[(cA_) * 8192];                              \
    const unsigned short* Bbuf = &lds[24576 + (cB_) * 8192];                      \
    bf16x8 afr[2][2];                                                             \
    _Pragma("unroll") for (int m2 = 0; m2 < 2; ++m2)                              \
        _Pragma("unroll") for (int kk = 0; kk < 2; ++kk)                          \
            afr[m2][kk] =                                                         \
        readfrag(Abuf, wm * 64 + ((P) * 2 + m2) * 16 + l15, kk * 64 + lg * 16);   \
    if ((P) == 0) {                                                               \
      _Pragma("unroll") for (int nf = 0; nf < 4; ++nf)                            \
          _Pragma("unroll") for (int kk = 0; kk < 2; ++kk)                        \
              bfr[nf][kk] =                                                       \
          readfrag(Bbuf, wn * 64 + nf * 16 + l15, kk * 64 + lg * 16);             \
    }                                                                             \
    STG;                                                                          \
    __builtin_amdgcn_sched_barrier(0);                                            \
    __builtin_amdgcn_s_barrier();                                                 \
    asm volatile("s_waitcnt lgkmcnt(0)" ::: "memory");                            \
    __builtin_amdgcn_sched_barrier(0);                                            \
    __builtin_amdgcn_s_setprio(1);                                                \
    _Pragma("unroll") for (int m2 = 0; m2 < 2; ++m2)                              \
        _Pragma("unroll") for (int nf = 0; nf < 4; ++nf)                          \
            _Pragma("unroll") for (int kk = 0; kk < 2; ++kk)                      \
                acc[(P) * 2 + m2][nf] =                                           \
        MFMA(afr[m2][kk], bfr[nf][kk], acc[(P) * 2 + m2][nf]);                    \
    __builtin_amdgcn_s_setprio(0);                                                \
    EW;                                                                           \
    __builtin_amdgcn_sched_barrier(0);                                            \
    __builtin_amdgcn_s_barrier();                                                 \
  }

  // main loop: iter t consumes A[t%3], B[t&1]; phase0 stages B(t+1),
  // phase1 stages A(t+2) LAST then vmcnt(4) -> leaves only A(t+2) in flight,
  // guarantees A(t+1),B(t+1) landed. Never drains to 0 in-loop.
  int cA = 0;
  for (int t = 0; t < 10; ++t) {
    int cB = t & 1, cBn = cB ^ 1;
    int cA2 = cA + 2; if (cA2 >= 3) cA2 -= 3;
    int k1 = (t + 1) * 64, k2 = (t + 2) * 64;
    GPHASE(cA, cB, 0, { SB(cBn, k1, 0); SB(cBn, k1, 1); SB(cBn, k1, 2); SB(cBn, k1, 3); }, );
    GPHASE(cA, cB, 1, { SA(cA2, k2, 0); SA(cA2, k2, 1); SA(cA2, k2, 2); SA(cA2, k2, 3); },
           asm volatile("s_waitcnt vmcnt(4)" ::: "memory"));
    cA = (cA == 2) ? 0 : cA + 1;
  }
  // t=10: stage only B(11); drain all at end
  GPHASE(cA, 0, 0, { SB(1, 704, 0); SB(1, 704, 1); SB(1, 704, 2); SB(1, 704, 3); }, );
  GPHASE(cA, 0, 1, , asm volatile("s_waitcnt vmcnt(0)" ::: "memory"));
  cA = (cA == 2) ? 0 : cA + 1;
  // t=11
  GPHASE(cA, 1, 0, , );
  GPHASE(cA, 1, 1, , );

  __syncthreads();  // reuse LDS for epilogue

  const int sec = n0 / 768;  // 0=q,1=k,2=v (block-uniform; 128 | 768)
  float bcol[4];
#pragma unroll
  for (int nf = 0; nf < 4; ++nf) bcol[nf] = bias[n0 + wn * 64 + nf * 16 + l15];

  if (sec < 2) {
    unsigned short* ct = lds;  // [128][128] = 16384 elems (fits 40960)
#pragma unroll
    for (int mf = 0; mf < 4; ++mf)
#pragma unroll
      for (int nf = 0; nf < 4; ++nf)
#pragma unroll
        for (int r = 0; r < 4; ++r)
          ct[(wm * 64 + mf * 16 + lg * 4 + r) * 128 + wn * 64 + nf * 16 + l15] =
              f2bf(acc[mf][nf][r] + bcol[nf]);
    __syncthreads();
    unsigned short* dstbase = (sec == 0) ? qb : kb;
    const int hbase = (n0 - sec * 768) >> 6;
    const int g8 = tid >> 3, l8 = tid & 7;  // 32 groups x 8 lanes
#pragma unroll
    for (int j = 0; j < 8; ++j) {
      int chunk = j * 32 + g8;  // 0..255 = row*2 + hh
      int row = chunk >> 1, hh = chunk & 1;
      us8 v = *(const us8*)&ct[row * 128 + hh * 64 + l8 * 8];
      int t = m0 + row, bb = t >> 10, tt = t & 1023;
      *(us8*)(dstbase + ((size_t)((bb * 12 + hbase + hh) * 1024 + tt)) * 64 + l8 * 8) = v;
    }
  } else {
    // v transposed [B,H,64,T]: us4 stores along t
#pragma unroll
    for (int nf = 0; nf < 4; ++nf) {
      int cc2 = (n0 - 1536) + wn * 64 + nf * 16 + l15;
      int h = cc2 >> 6, d = cc2 & 63;
#pragma unroll
      for (int mf = 0; mf < 4; ++mf) {
        int row0 = m0 + wm * 64 + mf * 16 + lg * 4;
        int bb = row0 >> 10, t0 = row0 & 1023;
        us4 o;
#pragma unroll
        for (int r = 0; r < 4; ++r) o[r] = f2bf(acc[mf][nf][r] + bcol[nf]);
        *(us4*)(vb + ((size_t)((bb * 12 + h) * 64 + d)) * 1024 + t0) = o;
      }
    }
  }
#undef SA
#undef SB
#undef GPHASE
}

// ---- kernel 4: causal ReLU attention (unchanged from R4) -------------------
__global__ __launch_bounds__(512, 2) void attn_kernel(
    const unsigned short* __restrict__ qb, const unsigned short* __restrict__ kb,
    const unsigned short* __restrict__ vb, float* __restrict__ out) {
  __shared__ unsigned short lds[65536];
  const int tid = threadIdx.x;
  const int lane = tid & 63, wid = tid >> 6;
  const int qs = wid >> 1, ks = wid & 1;
  const int l15 = lane & 15, lg = lane >> 4;

  int bid = blockIdx.x;
  int xcd = bid & 7, c = bid >> 3;       // c 0..47
  int bh = xcd * 12 + (c % 12);
  int byq = 3 - (c / 12);                // heavy q-blocks first
  const int b = bh / 12, h = bh % 12;
  const size_t base = (size_t)bh * 65536;
  const int Q = byq * 4 + qs;
  const int qr0 = byq * 256 + qs * 64;

  bf16x8 aq[4][2];
#pragma unroll
  for (int mf = 0; mf < 4; ++mf)
#pragma unroll
    for (int kk = 0; kk < 2; ++kk)
      aq[mf][kk] = *(const bf16x8*)(qb + base + (size_t)(qr0 + mf * 16 + l15) * 64 +
                                    kk * 32 + lg * 8);

  const int e = tid * 8;
  const int row = e >> 6;
  const int esw = e ^ ((row & 7) << 3);

#define ASTAGE(buf, i_)                                                            \
  {                                                                                \
    int kt0 = 2 * (i_);                                                            \
    gload16(kb + base + (size_t)kt0 * 4096 + esw, &lds[(buf) * 8192 + e]);         \
    gload16(kb + base + (size_t)(kt0 + 1) * 4096 + esw,                            \
            &lds[(buf) * 8192 + 4096 + e]);                                        \
    gload16(vb + base + (size_t)row * 1024 + kt0 * 64 + (esw & 63),                \
            &lds[16384 + (buf) * 8192 + e]);                                       \
    gload16(vb + base + (size_t)row * 1024 + (kt0 + 1) * 64 + (esw & 63),          \
            &lds[16384 + (buf) * 8192 + 4096 + e]);                                \
  }

  f32x4 o[4][4] = {};
  unsigned short* Sb = &lds[32768 + wid * 4096];

  const int niter = 2 * byq + 2;
  ASTAGE(0, 0);
  asm volatile("s_waitcnt vmcnt(0)" ::: "memory");
  __builtin_amdgcn_s_barrier();

  for (int i = 0; i < niter; ++i) {
    const int cur = i & 1;
    if (i + 1 < niter) ASTAGE(cur ^ 1, i + 1);
    const int kt = 2 * i + ks;
    if (kt <= Q) {
      const unsigned short* Kb = &lds[cur * 8192 + ks * 4096];
      const unsigned short* Vb = &lds[16384 + cur * 8192 + ks * 4096];
      bf16x8 bk[4][2];
#pragma unroll
      for (int nf = 0; nf < 4; ++nf)
#pragma unroll
        for (int kk = 0; kk < 2; ++kk)
          bk[nf][kk] = readfrag(Kb, nf * 16 + l15, kk * 64 + lg * 16);
      const bool diag = (kt == Q);
      __builtin_amdgcn_s_setprio(1);
#pragma unroll
      for (int mf = 0; mf < 4; ++mf)
#pragma unroll
        for (int nf = 0; nf < 4; ++nf) {
          f32x4 s = {};
          s = MFMA(aq[mf][0], bk[nf][0], s);
          s = MFMA(aq[mf][1], bk[nf][1], s);
          int colk = nf * 16 + l15;
#pragma unroll
          for (int r = 0; r < 4; ++r) {
            int rowq = mf * 16 + lg * 4 + r;
            float v = fmaxf(s[r] * 0.125f, 0.0f);
            if (diag && colk > rowq) v = 0.0f;
            int byte = (rowq * 128 + colk * 2) ^ ((rowq & 7) << 4);
            *(unsigned short*)((char*)Sb + byte) = f2bf(v);
          }
        }
      __builtin_amdgcn_s_setprio(0);
      bf16x8 pa[4][2];
#pragma unroll
      for (int mf = 0; mf < 4; ++mf)
#pragma unroll
        for (int kk = 0; kk < 2; ++kk)
          pa[mf][kk] = readfrag(Sb, mf * 16 + l15, kk * 64 + lg * 16);
      __builtin_amdgcn_s_setprio(1);
#pragma unroll
      for (int mf = 0; mf < 4; ++mf)
#pragma unroll
        for (int df = 0; df < 4; ++df)
#pragma unroll
          for (int kk = 0; kk < 2; ++kk)
            o[mf][df] = MFMA(pa[mf][kk], readfrag(Vb, df * 16 + l15, kk * 64 + lg * 16),
                             o[mf][df]);
      __builtin_amdgcn_s_setprio(0);
    }
    asm volatile("s_waitcnt vmcnt(0)" ::: "memory");
    __builtin_amdgcn_sched_barrier(0);
    __builtin_amdgcn_s_barrier();
  }
#undef ASTAGE

  float* fr = (float*)lds;
  if (ks == 1) {
#pragma unroll
    for (int mf = 0; mf < 4; ++mf)
#pragma unroll
      for (int df = 0; df < 4; ++df)
#pragma unroll
        for (int r = 0; r < 4; ++r) {
          int rowq = mf * 16 + lg * 4 + r, col = df * 16 + l15;
          int idx = (qs * 4096 + rowq * 64 + col) ^ ((rowq & 4) << 2);
          fr[idx] = o[mf][df][r];
        }
  }
  __syncthreads();
  if (ks == 0) {
#pragma unroll
    for (int mf = 0; mf < 4; ++mf)
#pragma unroll
      for (int df = 0; df < 4; ++df)
#pragma unroll
        for (int r = 0; r < 4; ++r) {
          int rowq = mf * 16 + lg * 4 + r, col = df * 16 + l15;
          int idx = (qs * 4096 + rowq * 64 + col) ^ ((rowq & 4) << 2);
          float v = o[mf][df][r] + fr[idx];
          out[(size_t)(b * 1024 + qr0 + rowq) * 768 + h * 64 + col] = v;
        }
  }
}

// ---- launch ----------------------------------------------------------------
extern "C" void kernel_launch(void* const* d_in, const int* in_sizes, int n_in,
                              void* d_out, int out_size, void* d_ws, size_t ws_size,
                              hipStream_t stream) {
  const float* x = (const float*)d_in[0];
  const float* W = (const float*)d_in[1];
  const float* bias = (const float*)d_in[2];
  float* out = (float*)d_out;

  unsigned short* xb = (unsigned short*)d_ws;  // 6291456 elems
  unsigned short* wt = xb + 6291456;           // 1769472 (Wt [2304][768])
  unsigned short* qb = wt + 1769472;           // [B,H,T,64]
  unsigned short* kb = qb + 6291456;
  unsigned short* vb = kb + 6291456;           // [B,H,64,T]

  cast_x_kernel<<<6144, 256, 0, stream>>>(x, xb, 1572864);
  castw_kernel<<<dim3(72, 24), 256, 0, stream>>>(W, wt);
  qkv_gemm_kernel<<<1152, 256, 0, stream>>>(xb, wt, bias, qb, kb, vb);
  attn_kernel<<<384, 512, 0, stream>>>(qb, kb, vb, out);
}

// Round 7
// 84.093 us; speedup vs baseline: 1.1763x; 1.0345x over previous
//
#include <hip/hip_runtime.h>

// ---- types ----------------------------------------------------------------
typedef __attribute__((ext_vector_type(8))) short bf16x8;     // 8 bf16 (4 VGPR)
typedef __attribute__((ext_vector_type(4))) float f32x4;
typedef __attribute__((ext_vector_type(4))) unsigned short us4;
typedef __attribute__((ext_vector_type(8))) unsigned short us8;

#define MFMA(a, b, c) __builtin_amdgcn_mfma_f32_16x16x32_bf16((a), (b), (c), 0, 0, 0)

__device__ __forceinline__ unsigned short f2bf(float f) {
  unsigned u = __builtin_bit_cast(unsigned, f);
  u = (u + 0x7fffu + ((u >> 16) & 1u)) >> 16;  // RNE
  return (unsigned short)u;
}

// packed f32x2 -> bf16x2 (RNE), 1 instruction
__device__ __forceinline__ unsigned cvt_pk_bf16(float lo, float hi) {
  unsigned r;
  asm("v_cvt_pk_bf16_f32 %0, %1, %2" : "=v"(r) : "v"(lo), "v"(hi));
  return r;
}

__device__ __forceinline__ void gload16(const void* g, void* l) {
  __builtin_amdgcn_global_load_lds((const __attribute__((address_space(1))) void*)g,
                                   (__attribute__((address_space(3))) void*)l,
                                   16, 0, 0);
}

// 128B-row swizzled fragment read: phys = byte ^ ((row&7)<<4).
__device__ __forceinline__ bf16x8 readfrag(const unsigned short* buf, int row, int kbyte) {
  int byte = row * 128 + kbyte;
  byte ^= (row & 7) << 4;
  return *(const bf16x8*)((const char*)buf + byte);
}

// ---- kernel 1: cast x -> bf16 (float4 vectorized) --------------------------
__global__ void cast_x_kernel(const float* __restrict__ x,
                              unsigned short* __restrict__ xb, int n4) {
  int id = blockIdx.x * blockDim.x + threadIdx.x;
  if (id >= n4) return;
  float4 v = ((const float4*)x)[id];
  us4 o = { f2bf(v.x), f2bf(v.y), f2bf(v.z), f2bf(v.w) };
  ((us4*)xb)[id] = o;
}

// ---- kernel 2: W [768][2304] -> Wt [2304][768] bf16 (tiled transpose) ------
__global__ void castw_kernel(const float* __restrict__ W,
                             unsigned short* __restrict__ Wt) {
  __shared__ unsigned short tile[32][33];
  int bn = blockIdx.x * 32;
  int bk = blockIdx.y * 32;
  int lx = threadIdx.x & 31, ly = threadIdx.x >> 5;  // 32 x 8
#pragma unroll
  for (int i = 0; i < 32; i += 8)
    tile[ly + i][lx] = f2bf(W[(bk + ly + i) * 2304 + bn + lx]);
  __syncthreads();
#pragma unroll
  for (int i = 0; i < 32; i += 8)
    Wt[(bn + ly + i) * 768 + bk + lx] = tile[lx][ly + i];
}

// ---- kernel 3: QKV GEMM (unchanged structure from R6; q scaled by 1/8) -----
__global__ __launch_bounds__(256, 2) void qkv_gemm_kernel(
    const unsigned short* __restrict__ xb, const unsigned short* __restrict__ wt,
    const float* __restrict__ bias,
    unsigned short* __restrict__ qb, unsigned short* __restrict__ kb,
    unsigned short* __restrict__ vb) {
  __shared__ unsigned short lds[40960];  // A 3x8192 elems @0, B 2x8192 @24576 = 80KB
  const int tid = threadIdx.x;
  const int lane = tid & 63, wid = tid >> 6;
  const int wm = wid >> 1, wn = wid & 1;   // wave-tile 64x64
  const int l15 = lane & 15, lg = lane >> 4;

  int bid = blockIdx.x;
  int xcd = bid & 7, c = bid >> 3;       // c 0..143
  int mb = xcd * 8 + (c & 7);            // 0..63
  int nb = c >> 3;                       // 0..17
  const int m0 = mb * 128, n0 = nb * 128;

  const unsigned short* Ab_g = xb + (size_t)m0 * 768;
  const unsigned short* Bb_g = wt + (size_t)n0 * 768;

  int eA[4], sA[4];
#pragma unroll
  for (int i = 0; i < 4; ++i) {
    int e = (i * 256 + tid) * 8, row = e >> 6;
    eA[i] = e;
    sA[i] = row * 768 + ((e ^ ((row & 7) << 3)) & 63);
  }

#define SA(buf, k0, i) gload16(Ab_g + sA[i] + (k0), &lds[(buf) * 8192 + eA[i]])
#define SB(buf, k0, i) gload16(Bb_g + sA[i] + (k0), &lds[24576 + (buf) * 8192 + eA[i]])

  f32x4 acc[4][4] = {};
  bf16x8 bfr[4][2];

  SA(0, 0, 0); SA(0, 0, 1); SA(0, 0, 2); SA(0, 0, 3);
  SB(0, 0, 0); SB(0, 0, 1); SB(0, 0, 2); SB(0, 0, 3);
  SA(1, 64, 0); SA(1, 64, 1); SA(1, 64, 2); SA(1, 64, 3);
  asm volatile("s_waitcnt vmcnt(4)" ::: "memory");
  __builtin_amdgcn_s_barrier();

#define GPHASE(cA_, cB_, P, STG, EW)                                              \
  {                                                                               \
    const unsigned short* Abuf = &lds[(cA_) * 8192];                              \
    const unsigned short* Bbuf = &lds[24576 + (cB_) * 8192];                      \
    bf16x8 afr[2][2];                                                             \
    _Pragma("unroll") for (int m2 = 0; m2 < 2; ++m2)                              \
        _Pragma("unroll") for (int kk = 0; kk < 2; ++kk)                          \
            afr[m2][kk] =                                                         \
        readfrag(Abuf, wm * 64 + ((P) * 2 + m2) * 16 + l15, kk * 64 + lg * 16);   \
    if ((P) == 0) {                                                               \
      _Pragma("unroll") for (int nf = 0; nf < 4; ++nf)                            \
          _Pragma("unroll") for (int kk = 0; kk < 2; ++kk)                        \
              bfr[nf][kk] =                                                       \
          readfrag(Bbuf, wn * 64 + nf * 16 + l15, kk * 64 + lg * 16);             \
    }                                                                             \
    STG;                                                                          \
    __builtin_amdgcn_sched_barrier(0);                                            \
    __builtin_amdgcn_s_barrier();                                                 \
    asm volatile("s_waitcnt lgkmcnt(0)" ::: "memory");                            \
    __builtin_amdgcn_sched_barrier(0);                                            \
    __builtin_amdgcn_s_setprio(1);                                                \
    _Pragma("unroll") for (int m2 = 0; m2 < 2; ++m2)                              \
        _Pragma("unroll") for (int nf = 0; nf < 4; ++nf)                          \
            _Pragma("unroll") for (int kk = 0; kk < 2; ++kk)                      \
                acc[(P) * 2 + m2][nf] =                                           \
        MFMA(afr[m2][kk], bfr[nf][kk], acc[(P) * 2 + m2][nf]);                    \
    __builtin_amdgcn_s_setprio(0);                                                \
    EW;                                                                           \
    __builtin_amdgcn_sched_barrier(0);                                            \
    __builtin_amdgcn_s_barrier();                                                 \
  }

  int cA = 0;
  for (int t = 0; t < 10; ++t) {
    int cB = t & 1, cBn = cB ^ 1;
    int cA2 = cA + 2; if (cA2 >= 3) cA2 -= 3;
    int k1 = (t + 1) * 64, k2 = (t + 2) * 64;
    GPHASE(cA, cB, 0, { SB(cBn, k1, 0); SB(cBn, k1, 1); SB(cBn, k1, 2); SB(cBn, k1, 3); }, );
    GPHASE(cA, cB, 1, { SA(cA2, k2, 0); SA(cA2, k2, 1); SA(cA2, k2, 2); SA(cA2, k2, 3); },
           asm volatile("s_waitcnt vmcnt(4)" ::: "memory"));
    cA = (cA == 2) ? 0 : cA + 1;
  }
  GPHASE(cA, 0, 0, { SB(1, 704, 0); SB(1, 704, 1); SB(1, 704, 2); SB(1, 704, 3); }, );
  GPHASE(cA, 0, 1, , asm volatile("s_waitcnt vmcnt(0)" ::: "memory"));
  cA = (cA == 2) ? 0 : cA + 1;
  GPHASE(cA, 1, 0, , );
  GPHASE(cA, 1, 1, , );

  __syncthreads();  // reuse LDS for epilogue

  const int sec = n0 / 768;  // 0=q,1=k,2=v (block-uniform; 128 | 768)
  // fold attention scale 1/sqrt(64) into q (exact in bf16: pow2 exponent shift)
  const float qs = (sec == 0) ? 0.125f : 1.0f;
  float bcol[4];
#pragma unroll
  for (int nf = 0; nf < 4; ++nf) bcol[nf] = bias[n0 + wn * 64 + nf * 16 + l15];

  if (sec < 2) {
    unsigned short* ct = lds;  // [128][128]
#pragma unroll
    for (int mf = 0; mf < 4; ++mf)
#pragma unroll
      for (int nf = 0; nf < 4; ++nf)
#pragma unroll
        for (int r = 0; r < 4; ++r)
          ct[(wm * 64 + mf * 16 + lg * 4 + r) * 128 + wn * 64 + nf * 16 + l15] =
              f2bf((acc[mf][nf][r] + bcol[nf]) * qs);
    __syncthreads();
    unsigned short* dstbase = (sec == 0) ? qb : kb;
    const int hbase = (n0 - sec * 768) >> 6;
    const int g8 = tid >> 3, l8 = tid & 7;
#pragma unroll
    for (int j = 0; j < 8; ++j) {
      int chunk = j * 32 + g8;  // 0..255 = row*2 + hh
      int row = chunk >> 1, hh = chunk & 1;
      us8 v = *(const us8*)&ct[row * 128 + hh * 64 + l8 * 8];
      int t = m0 + row, bb = t >> 10, tt = t & 1023;
      *(us8*)(dstbase + ((size_t)((bb * 12 + hbase + hh) * 1024 + tt)) * 64 + l8 * 8) = v;
    }
  } else {
#pragma unroll
    for (int nf = 0; nf < 4; ++nf) {
      int cc2 = (n0 - 1536) + wn * 64 + nf * 16 + l15;
      int h = cc2 >> 6, d = cc2 & 63;
#pragma unroll
      for (int mf = 0; mf < 4; ++mf) {
        int row0 = m0 + wm * 64 + mf * 16 + lg * 4;
        int bb = row0 >> 10, t0 = row0 & 1023;
        us4 o;
#pragma unroll
        for (int r = 0; r < 4; ++r) o[r] = f2bf(acc[mf][nf][r] + bcol[nf]);
        *(us4*)(vb + ((size_t)((bb * 12 + h) * 64 + d)) * 1024 + t0) = o;
      }
    }
  }
#undef SA
#undef SB
#undef GPHASE
}

// ---- kernel 4: causal ReLU attention ---------------------------------------
// Swapped QK^T: s^T = mfma(K-frag, Q-frag) -> per lane 4 consecutive k at
// fixed q -> 2x cvt_pk + one ds_write_b64 per 16x16 tile (was 64 scalar
// writes + 64 manual casts). PV unchanged. q pre-scaled by 1/8 in GEMM.
__global__ __launch_bounds__(512, 2) void attn_kernel(
    const unsigned short* __restrict__ qb, const unsigned short* __restrict__ kb,
    const unsigned short* __restrict__ vb, float* __restrict__ out) {
  __shared__ unsigned short lds[65536];
  const int tid = threadIdx.x;
  const int lane = tid & 63, wid = tid >> 6;
  const int qs = wid >> 1, ks = wid & 1;
  const int l15 = lane & 15, lg = lane >> 4;

  int bid = blockIdx.x;
  int xcd = bid & 7, c = bid >> 3;       // c 0..47
  int bh = xcd * 12 + (c % 12);
  int byq = 3 - (c / 12);                // heavy q-blocks first
  const int b = bh / 12, h = bh % 12;
  const size_t base = (size_t)bh * 65536;
  const int Q = byq * 4 + qs;
  const int qr0 = byq * 256 + qs * 64;

  bf16x8 aq[4][2];
#pragma unroll
  for (int mf = 0; mf < 4; ++mf)
#pragma unroll
    for (int kk = 0; kk < 2; ++kk)
      aq[mf][kk] = *(const bf16x8*)(qb + base + (size_t)(qr0 + mf * 16 + l15) * 64 +
                                    kk * 32 + lg * 8);

  const int e = tid * 8;
  const int row = e >> 6;
  const int esw = e ^ ((row & 7) << 3);

#define ASTAGE(buf, i_)                                                            \
  {                                                                                \
    int kt0 = 2 * (i_);                                                            \
    gload16(kb + base + (size_t)kt0 * 4096 + esw, &lds[(buf) * 8192 + e]);         \
    gload16(kb + base + (size_t)(kt0 + 1) * 4096 + esw,                            \
            &lds[(buf) * 8192 + 4096 + e]);                                        \
    gload16(vb + base + (size_t)row * 1024 + kt0 * 64 + (esw & 63),                \
            &lds[16384 + (buf) * 8192 + e]);                                       \
    gload16(vb + base + (size_t)row * 1024 + (kt0 + 1) * 64 + (esw & 63),          \
            &lds[16384 + (buf) * 8192 + 4096 + e]);                                \
  }

  f32x4 o[4][4] = {};
  unsigned short* Sb = &lds[32768 + wid * 4096];

  const int niter = 2 * byq + 2;
  ASTAGE(0, 0);
  asm volatile("s_waitcnt vmcnt(0)" ::: "memory");
  __builtin_amdgcn_s_barrier();

  for (int i = 0; i < niter; ++i) {
    const int cur = i & 1;
    if (i + 1 < niter) ASTAGE(cur ^ 1, i + 1);
    const int kt = 2 * i + ks;
    if (kt <= Q) {
      const unsigned short* Kb = &lds[cur * 8192 + ks * 4096];
      const unsigned short* Vb = &lds[16384 + cur * 8192 + ks * 4096];
      bf16x8 bk[4][2];
#pragma unroll
      for (int nf = 0; nf < 4; ++nf)
#pragma unroll
        for (int kk = 0; kk < 2; ++kk)
          bk[nf][kk] = readfrag(Kb, nf * 16 + l15, kk * 64 + lg * 16);
      const bool diag = (kt == Q);
      __builtin_amdgcn_s_setprio(1);
#pragma unroll
      for (int mf = 0; mf < 4; ++mf)
#pragma unroll
        for (int nf = 0; nf < 4; ++nf) {
          // s^T tile: row = k (nf*16 + lg*4 + r), col = q (mf*16 + l15)
          f32x4 s = {};
          s = MFMA(bk[nf][0], aq[mf][0], s);
          s = MFMA(bk[nf][1], aq[mf][1], s);
          float v0, v1, v2, v3;
          if (diag) {
            int q = mf * 16 + l15, k0 = nf * 16 + lg * 4;
            v0 = (k0 + 0 <= q) ? fmaxf(s[0], 0.0f) : 0.0f;
            v1 = (k0 + 1 <= q) ? fmaxf(s[1], 0.0f) : 0.0f;
            v2 = (k0 + 2 <= q) ? fmaxf(s[2], 0.0f) : 0.0f;
            v3 = (k0 + 3 <= q) ? fmaxf(s[3], 0.0f) : 0.0f;
          } else {
            v0 = fmaxf(s[0], 0.0f);
            v1 = fmaxf(s[1], 0.0f);
            v2 = fmaxf(s[2], 0.0f);
            v3 = fmaxf(s[3], 0.0f);
          }
          uint2 w;
          w.x = cvt_pk_bf16(v0, v1);
          w.y = cvt_pk_bf16(v2, v3);
          // S[q][k]: 4 consecutive k at fixed q -> one b64 store (swizzled)
          int rowq = mf * 16 + l15;
          int byte = (rowq * 128 + (nf * 16 + lg * 4) * 2) ^ ((rowq & 7) << 4);
          *(uint2*)((char*)Sb + byte) = w;
        }
      __builtin_amdgcn_s_setprio(0);
      // O += S @ V (wave-private S; compiler orders via lgkmcnt)
      bf16x8 pa[4][2];
#pragma unroll
      for (int mf = 0; mf < 4; ++mf)
#pragma unroll
        for (int kk = 0; kk < 2; ++kk)
          pa[mf][kk] = readfrag(Sb, mf * 16 + l15, kk * 64 + lg * 16);
      __builtin_amdgcn_s_setprio(1);
#pragma unroll
      for (int mf = 0; mf < 4; ++mf)
#pragma unroll
        for (int df = 0; df < 4; ++df)
#pragma unroll
          for (int kk = 0; kk < 2; ++kk)
            o[mf][df] = MFMA(pa[mf][kk], readfrag(Vb, df * 16 + l15, kk * 64 + lg * 16),
                             o[mf][df]);
      __builtin_amdgcn_s_setprio(0);
    }
    asm volatile("s_waitcnt vmcnt(0)" ::: "memory");
    __builtin_amdgcn_sched_barrier(0);
    __builtin_amdgcn_s_barrier();
  }
#undef ASTAGE

  float* fr = (float*)lds;
  if (ks == 1) {
#pragma unroll
    for (int mf = 0; mf < 4; ++mf)
#pragma unroll
      for (int df = 0; df < 4; ++df)
#pragma unroll
        for (int r = 0; r < 4; ++r) {
          int rowq = mf * 16 + lg * 4 + r, col = df * 16 + l15;
          int idx = (qs * 4096 + rowq * 64 + col) ^ ((rowq & 4) << 2);
          fr[idx] = o[mf][df][r];
        }
  }
  __syncthreads();
  if (ks == 0) {
#pragma unroll
    for (int mf = 0; mf < 4; ++mf)
#pragma unroll
      for (int df = 0; df < 4; ++df)
#pragma unroll
        for (int r = 0; r < 4; ++r) {
          int rowq = mf * 16 + lg * 4 + r, col = df * 16 + l15;
          int idx = (qs * 4096 + rowq * 64 + col) ^ ((rowq & 4) << 2);
          float v = o[mf][df][r] + fr[idx];
          out[(size_t)(b * 1024 + qr0 + rowq) * 768 + h * 64 + col] = v;
        }
  }
}

// ---- launch ----------------------------------------------------------------
extern "C" void kernel_launch(void* const* d_in, const int* in_sizes, int n_in,
                              void* d_out, int out_size, void* d_ws, size_t ws_size,
                              hipStream_t stream) {
  const float* x = (const float*)d_in[0];
  const float* W = (const float*)d_in[1];
  const float* bias = (const float*)d_in[2];
  float* out = (float*)d_out;

  unsigned short* xb = (unsigned short*)d_ws;  // 6291456 elems
  unsigned short* wt = xb + 6291456;           // 1769472 (Wt [2304][768])
  unsigned short* qb = wt + 1769472;           // [B,H,T,64]  (q pre-scaled by 1/8)
  unsigned short* kb = qb + 6291456;
  unsigned short* vb = kb + 6291456;           // [B,H,64,T]

  cast_x_kernel<<<6144, 256, 0, stream>>>(x, xb, 1572864);
  castw_kernel<<<dim3(72, 24), 256, 0, stream>>>(W, wt);
  qkv_gemm_kernel<<<1152, 256, 0, stream>>>(xb, wt, bias, qb, kb, vb);
  attn_kernel<<<384, 512, 0, stream>>>(qb, kb, vb, out);
}